// Round 15
// baseline (24213.391 us; speedup 1.0000x reference)
//
#include <hip/hip_runtime.h>
#include <hip/hip_bf16.h>
#include <hip/hip_cooperative_groups.h>
#include <cstdint>
#include <cstddef>

namespace cg = cooperative_groups;

#define NB 32
#define NL 256
#define NH 512
#define NE 512
#define NV 32000
#define NT 64
#define NJ 2048   // 4*H
#define NK 1024   // E+H
#define NKT 16    // k-chunks in gates partial GEMM (NK/64)

typedef __attribute__((ext_vector_type(8))) short bf16x8;
typedef __attribute__((ext_vector_type(4))) float f32x4;

// ---------------- helpers ----------------

__device__ __forceinline__ unsigned int sortable_f32(float f) {
  unsigned int s = __float_as_uint(f);
  return (s & 0x80000000u) ? ~s : (s | 0x80000000u);
}

__device__ __forceinline__ unsigned long long pack_key(float f, int v) {
  // high 32: sortable float; low 32: ~v so ties pick smallest v (numpy argmax)
  return ((unsigned long long)sortable_f32(f) << 32) |
         (unsigned long long)(unsigned int)(~v);
}

__device__ __forceinline__ unsigned long long shfl_xor_u64(unsigned long long x, int m) {
  unsigned int lo = (unsigned int)x;
  unsigned int hi = (unsigned int)(x >> 32);
  lo = __shfl_xor(lo, m, 64);
  hi = __shfl_xor(hi, m, 64);
  return ((unsigned long long)hi << 32) | lo;
}

__device__ __forceinline__ uint32_t pack_hi16(uint32_t u0, uint32_t u1) {
  // result = [hi16(u0) in low half, hi16(u1) in high half]
  return __builtin_amdgcn_perm(u1, u0, 0x07060302u);
}

// exact 3-way bf16 truncation split of 8 fp32 values: e == A1 + A2 + A3 bitwise
__device__ __forceinline__ void split3(float4 wa, float4 wb,
                                       bf16x8& A1, bf16x8& A2, bf16x8& A3) {
  union U { uint32_t w[4]; bf16x8 v; };
  U u1, u2, u3;
  float e[8] = {wa.x, wa.y, wa.z, wa.w, wb.x, wb.y, wb.z, wb.w};
#pragma unroll
  for (int p = 0; p < 4; ++p) {
    float e0 = e[2 * p], e1 = e[2 * p + 1];
    uint32_t a0 = __float_as_uint(e0), a1 = __float_as_uint(e1);
    u1.w[p] = pack_hi16(a0, a1);
    float r0 = e0 - __uint_as_float(a0 & 0xffff0000u);
    float r1 = e1 - __uint_as_float(a1 & 0xffff0000u);
    uint32_t b0 = __float_as_uint(r0), b1 = __float_as_uint(r1);
    u2.w[p] = pack_hi16(b0, b1);
    float q0 = r0 - __uint_as_float(b0 & 0xffff0000u);
    float q1 = r1 - __uint_as_float(b1 & 0xffff0000u);
    u3.w[p] = pack_hi16(__float_as_uint(q0), __float_as_uint(q1));
  }
  A1 = u1.v; A2 = u2.v; A3 = u3.v;
}

// device-scope coherent key load
__device__ __forceinline__ unsigned long long load_key(const unsigned long long* p) {
  return __hip_atomic_load(p, __ATOMIC_ACQUIRE, __HIP_MEMORY_SCOPE_AGENT);
}

// ---------------- pre-kernels (one-time) ----------------

// K0: h0 = z@Wh.T + bh ; c0 = z@Wc.T + bc ; zero argmax keys
__global__ void k_init(const float* __restrict__ z, const float* __restrict__ Wh,
                       const float* __restrict__ bh, const float* __restrict__ Wc,
                       const float* __restrict__ bc, float* __restrict__ hbuf,
                       float* __restrict__ cbuf, unsigned long long* __restrict__ keys) {
  int idx = blockIdx.x * 256 + threadIdx.x;   // 0..16383
  int b = idx >> 9, hh = idx & 511;
  const float* zr  = z + b * NL;
  const float* whr = Wh + hh * NL;
  const float* wcr = Wc + hh * NL;
  float ah = 0.f, ac = 0.f;
  for (int k = 0; k < NL; ++k) {
    float zv = zr[k];
    ah += zv * whr[k];
    ac += zv * wcr[k];
  }
  hbuf[b * NH + hh] = ah + bh[hh];   // hbuf slot 0 (input of step 0; also x0)
  cbuf[b * NH + hh] = ac + bc[hh];
  if (idx < 64)
    __hip_atomic_store(&keys[idx], 0ULL, __ATOMIC_RELEASE, __HIP_MEMORY_SCOPE_AGENT);
}

// K0b: WT[k][j] = (k<E ? Wih[j][k] : Whh[j][k-E])   (tiled transpose, once)
__global__ void k_transposeW(const float* __restrict__ Wih, const float* __restrict__ Whh,
                             float* __restrict__ WT) {
  __shared__ float tile[32][33];
  int j0 = blockIdx.x * 32;
  int k0 = blockIdx.y * 32;
  int tx = threadIdx.x & 31;
  int ty = threadIdx.x >> 5;
  for (int r = ty; r < 32; r += 8) {
    int j = j0 + r, k = k0 + tx;
    tile[r][tx] = (k < NE) ? Wih[j * NE + k] : Whh[j * NH + (k - NE)];
  }
  __syncthreads();
  for (int r = ty; r < 32; r += 8) {
    int k = k0 + r, j = j0 + tx;
    WT[(size_t)k * NJ + j] = tile[tx][r];
  }
}

// K0c: one-time pack of Wfc into wave-linear fp32 fragments (no precision change).
__global__ void k_packW32(const float* __restrict__ Wfc, float* __restrict__ Wp32) {
  int bid = blockIdx.x;                 // wg in [0,2000)
  int tid = threadIdx.x;
  int lane = tid & 63, wv = tid >> 6;
  int r16 = lane & 15, g = lane >> 4;
  const float* wr = Wfc + (size_t)(bid * 16 + r16) * NH + g * 8;
#pragma unroll
  for (int q = 0; q < 4; ++q) {
    int kq = wv * 4 + q;
    float4 wa = *(const float4*)(wr + kq * 32);
    float4 wb = *(const float4*)(wr + kq * 32 + 4);
    float* dst = Wp32 + ((size_t)(bid * 16 + kq) << 9) + lane * 8;
    *(float4*)dst = wa;
    *(float4*)(dst + 4) = wb;
  }
}

// ---------------- the persistent cooperative decoder ----------------
// 256 blocks x 512 threads, 1 block/CU (LDS 117KB). Per step:
//   gates (r11 k_gates verbatim; bid -> (jx, kt)) -> fence+sync
//   cell  (r11 k_cell verbatim; 256 blocks x 64 thr) -> fence+sync
//   logits(r11 k_logits3 verbatim; blocks 0..249, 8 waves) -> fence+sync
__global__ __launch_bounds__(512, 1) void decoder(
    const float* __restrict__ WT, const float* __restrict__ emb,
    const float* __restrict__ bih, const float* __restrict__ bhh,
    const float* __restrict__ Wp32, const float* __restrict__ bfc,
    float* __restrict__ out, float* __restrict__ hbuf, float* __restrict__ cbuf,
    unsigned short* __restrict__ hs, unsigned long long* __restrict__ keys,
    float* __restrict__ partials) {
  cg::grid_group grid = cg::this_grid();

  __shared__ union {
    struct {
      __align__(16) unsigned short H[3][32][520];  // 99,840 B
      __align__(16) float tbuf[32][132];           // 16,896 B
    } lg;
    unsigned int spred[NB];
  } sm;
  __shared__ unsigned long long kmax[32];

  const int tid = threadIdx.x;
  const int bid = blockIdx.x;
  const int lane = tid & 63, wid = tid >> 6;
  const int r16 = lane & 15, g = lane >> 4;

  for (int t = 0; t < NT; ++t) {
    // ================= gates phase (all 256 blocks) =================
    {
      const int jx = bid & 15, ktb = bid >> 4;
      const int k0 = ktb * 64;
      const bool isx = (k0 < NE);
      const float* hin = hbuf + (size_t)(t & 1) * NB * NH;

      if (t > 0 && isx && tid < NB) {
        unsigned long long key = load_key(&keys[((t - 1) & 1) * NB + tid]);
        unsigned int pred = ~(unsigned int)(key & 0xFFFFFFFFu);
        if (pred >= NV) pred = 0;     // defensive; never triggers in a correct run
        sm.spred[tid] = pred;
      }
      __syncthreads();

      if (tid < 256) {
        const int jthr = tid & 31, bthr = tid >> 5;
        const int j0 = jx * 128 + jthr * 4;
        const int b0 = bthr * 4;

        const float* xp[4];
#pragma unroll
        for (int i = 0; i < 4; ++i) {
          int b = b0 + i;
          if (!isx) {
            xp[i] = hin + (size_t)b * NH - NE;
          } else if (t == 0) {
            xp[i] = hin + (size_t)b * NE;   // x0 = h0 (E==H)
          } else {
            xp[i] = emb + (size_t)sm.spred[b] * NE;
          }
        }

        float acc[4][4];
#pragma unroll
        for (int jj = 0; jj < 4; ++jj)
#pragma unroll
          for (int i = 0; i < 4; ++i) acc[jj][i] = 0.f;

#pragma unroll 4
        for (int k = k0; k < k0 + 64; ++k) {
          float4 w = *(const float4*)(WT + (size_t)k * NJ + j0);
#pragma unroll
          for (int i = 0; i < 4; ++i) {
            float xv = xp[i][k];
            acc[0][i] += w.x * xv;
            acc[1][i] += w.y * xv;
            acc[2][i] += w.z * xv;
            acc[3][i] += w.w * xv;
          }
        }

#pragma unroll
        for (int jj = 0; jj < 4; ++jj)
#pragma unroll
          for (int i = 0; i < 4; ++i)
            partials[((size_t)(j0 + jj) * NB + (b0 + i)) * NKT + ktb] = acc[jj][i];
      }
    }
    __threadfence();
    grid.sync();
    __threadfence();

    // ================= cell phase (256 blocks x 64 threads) =================
    if (tid < 64) {
      const int idx = bid * 64 + tid;          // 0..16383
      const int b = idx >> 9, hh = idx & 511;
      float g4[4];
#pragma unroll
      for (int gg2 = 0; gg2 < 4; ++gg2) {
        int j = gg2 * NH + hh;
        const float4* p4 = (const float4*)(partials + ((size_t)j * NB + b) * NKT);
        float4 a0 = p4[0], a1 = p4[1], a2 = p4[2], a3 = p4[3];
        float s = ((a0.x + a0.y) + (a0.z + a0.w)) + ((a1.x + a1.y) + (a1.z + a1.w)) +
                  ((a2.x + a2.y) + (a2.z + a2.w)) + ((a3.x + a3.y) + (a3.z + a3.w));
        g4[gg2] = s + bih[j] + bhh[j];
      }
      float ig = 1.0f / (1.0f + expf(-g4[0]));
      float fg = 1.0f / (1.0f + expf(-g4[1]));
      float gg = tanhf(g4[2]);
      float og = 1.0f / (1.0f + expf(-g4[3]));
      float c  = cbuf[b * NH + hh];
      float cn = fg * c + ig * gg;
      float hn = og * tanhf(cn);
      cbuf[b * NH + hh] = cn;
      hbuf[(size_t)((t + 1) & 1) * NB * NH + b * NH + hh] = hn;

      // exact 3-way bf16 truncation split: hn == h1 + h2 + h3
      uint32_t u = __float_as_uint(hn);
      float r1 = hn - __uint_as_float(u & 0xffff0000u);
      uint32_t u2 = __float_as_uint(r1);
      float r2 = r1 - __uint_as_float(u2 & 0xffff0000u);
      uint32_t u3 = __float_as_uint(r2);
      hs[0 * NB * NH + b * NH + hh] = (unsigned short)(u >> 16);
      hs[1 * NB * NH + b * NH + hh] = (unsigned short)(u2 >> 16);
      hs[2 * NB * NH + b * NH + hh] = (unsigned short)(u3 >> 16);

      if (idx < NB)
        __hip_atomic_store(&keys[(t & 1) * NB + idx], 0ULL,
                           __ATOMIC_RELEASE, __HIP_MEMORY_SCOPE_AGENT);
    }
    __threadfence();
    grid.sync();
    __threadfence();

    // ================= logits phase (blocks 0..249, 8 waves) =================
    if (bid < 250) {
      const int wg = bid * 8 + wid;                       // [0,2000)
      const float* wbase = Wp32 + ((size_t)wg << 13) + lane * 8;

      // prologue: raw fp32 for kq=0,1 (overlaps the LDS staging below)
      float4 wa0 = *(const float4*)(wbase);
      float4 wb0 = *(const float4*)(wbase + 4);
      float4 wan = *(const float4*)(wbase + 512);
      float4 wbn = *(const float4*)(wbase + 512 + 4);

      // stage all 3 h-split planes: 6144 float4, 12 per thread, coalesced
#pragma unroll
      for (int i = 0; i < 12; ++i) {
        int idx = tid + i * 512;
        int s = idx >> 11, rem = idx & 2047;
        int row = rem >> 6, ch = rem & 63;
        float4 d = *(const float4*)(hs + (size_t)s * (NB * NH) + row * NH + ch * 8);
        *(float4*)(&sm.lg.H[s][row][ch * 8]) = d;
      }
      if (tid < 32) kmax[tid] = 0ULL;

      bf16x8 Acur[3];
      split3(wa0, wb0, Acur[0], Acur[1], Acur[2]);
      __syncthreads();

      f32x4 acc0 = {0.f, 0.f, 0.f, 0.f};
      f32x4 acc1 = {0.f, 0.f, 0.f, 0.f};

#pragma unroll
      for (int kq = 0; kq < 16; ++kq) {
        float4 wa2, wb2;
        if (kq < 14) {
          wa2 = *(const float4*)(wbase + (size_t)(kq + 2) * 512);
          wb2 = *(const float4*)(wbase + (size_t)(kq + 2) * 512 + 4);
        }
        bf16x8 Anx[3];
        if (kq < 15) split3(wan, wbn, Anx[0], Anx[1], Anx[2]);

        const int ko = kq * 32 + g * 8;
        bf16x8 B1n0 = *(const bf16x8*)(&sm.lg.H[0][r16][ko]);
        bf16x8 B1n1 = *(const bf16x8*)(&sm.lg.H[0][r16 + 16][ko]);
        bf16x8 B2n0 = *(const bf16x8*)(&sm.lg.H[1][r16][ko]);
        bf16x8 B2n1 = *(const bf16x8*)(&sm.lg.H[1][r16 + 16][ko]);
        bf16x8 B3n0 = *(const bf16x8*)(&sm.lg.H[2][r16][ko]);
        bf16x8 B3n1 = *(const bf16x8*)(&sm.lg.H[2][r16 + 16][ko]);

        acc0 = __builtin_amdgcn_mfma_f32_16x16x32_bf16(Acur[0], B1n0, acc0, 0, 0, 0);
        acc0 = __builtin_amdgcn_mfma_f32_16x16x32_bf16(Acur[0], B2n0, acc0, 0, 0, 0);
        acc0 = __builtin_amdgcn_mfma_f32_16x16x32_bf16(Acur[1], B1n0, acc0, 0, 0, 0);
        acc0 = __builtin_amdgcn_mfma_f32_16x16x32_bf16(Acur[1], B2n0, acc0, 0, 0, 0);
        acc0 = __builtin_amdgcn_mfma_f32_16x16x32_bf16(Acur[0], B3n0, acc0, 0, 0, 0);
        acc0 = __builtin_amdgcn_mfma_f32_16x16x32_bf16(Acur[2], B1n0, acc0, 0, 0, 0);

        acc1 = __builtin_amdgcn_mfma_f32_16x16x32_bf16(Acur[0], B1n1, acc1, 0, 0, 0);
        acc1 = __builtin_amdgcn_mfma_f32_16x16x32_bf16(Acur[0], B2n1, acc1, 0, 0, 0);
        acc1 = __builtin_amdgcn_mfma_f32_16x16x32_bf16(Acur[1], B1n1, acc1, 0, 0, 0);
        acc1 = __builtin_amdgcn_mfma_f32_16x16x32_bf16(Acur[1], B2n1, acc1, 0, 0, 0);
        acc1 = __builtin_amdgcn_mfma_f32_16x16x32_bf16(Acur[0], B3n1, acc1, 0, 0, 0);
        acc1 = __builtin_amdgcn_mfma_f32_16x16x32_bf16(Acur[2], B1n1, acc1, 0, 0, 0);

        if (kq < 15) {
#pragma unroll
          for (int s = 0; s < 3; ++s) Acur[s] = Anx[s];
          wan = wa2; wbn = wb2;
        }
      }

      // epilogue: bias, argmax keys, transposed coalesced store
      const int vwave = bid * 128 + wid * 16;
      float4 bv = *(const float4*)(bfc + vwave + g * 4);
      float lg0[4], lg1[4];
      unsigned long long key0 = 0ULL, key1 = 0ULL;
#pragma unroll
      for (int reg = 0; reg < 4; ++reg) {
        int v = vwave + 4 * g + reg;
        float bvr = (reg == 0) ? bv.x : (reg == 1) ? bv.y : (reg == 2) ? bv.z : bv.w;
        lg0[reg] = acc0[reg] + bvr;
        lg1[reg] = acc1[reg] + bvr;
        unsigned long long p0 = pack_key(lg0[reg], v);
        unsigned long long p1 = pack_key(lg1[reg], v);
        key0 = (p0 > key0) ? p0 : key0;
        key1 = (p1 > key1) ? p1 : key1;
      }
#pragma unroll
      for (int m = 16; m <= 32; m <<= 1) {
        unsigned long long o0 = shfl_xor_u64(key0, m);
        unsigned long long o1 = shfl_xor_u64(key1, m);
        key0 = (o0 > key0) ? o0 : key0;
        key1 = (o1 > key1) ? o1 : key1;
      }
      if (g == 0) {
        atomicMax(&kmax[r16], key0);
        atomicMax(&kmax[r16 + 16], key1);
      }
      __syncthreads();   // kmax atomics + last H reads complete

      // write transposed tile: tbuf[b][v_local]
#pragma unroll
      for (int reg = 0; reg < 4; ++reg) {
        int vloc = wid * 16 + 4 * g + reg;
        sm.lg.tbuf[r16][vloc] = lg0[reg];
        sm.lg.tbuf[r16 + 16][vloc] = lg1[reg];
      }
      __syncthreads();

      // coalesced nontemporal store: 128 x 32 tile, 8 per thread
      {
        int bb = tid >> 4, seg = tid & 15;
        f32x4 p0 = *(const f32x4*)(&sm.lg.tbuf[bb][seg * 8]);
        f32x4 p1 = *(const f32x4*)(&sm.lg.tbuf[bb][seg * 8 + 4]);
        float* dst = out + ((size_t)bb * NT + t) * NV + bid * 128 + seg * 8;
        __builtin_nontemporal_store(p0, (f32x4*)dst);
        __builtin_nontemporal_store(p1, (f32x4*)(dst + 4));
      }
      if (tid < 32) atomicMax(&keys[(t & 1) * NB + tid], kmax[tid]);
    }
    __threadfence();
    grid.sync();
    __threadfence();
  }
}

// ---------------- host ----------------

extern "C" void kernel_launch(void* const* d_in, const int* in_sizes, int n_in,
                              void* d_out, int out_size, void* d_ws, size_t ws_size,
                              hipStream_t stream) {
  (void)in_sizes; (void)n_in; (void)out_size; (void)ws_size;
  const float* z   = (const float*)d_in[0];
  const float* emb = (const float*)d_in[1];
  const float* Wh  = (const float*)d_in[2];
  const float* bh  = (const float*)d_in[3];
  const float* Wc  = (const float*)d_in[4];
  const float* bc  = (const float*)d_in[5];
  const float* Wih = (const float*)d_in[6];
  const float* Whh = (const float*)d_in[7];
  const float* bih = (const float*)d_in[8];
  const float* bhh = (const float*)d_in[9];
  const float* Wfc = (const float*)d_in[10];
  const float* bfc = (const float*)d_in[11];
  float* out = (float*)d_out;

  float* ws = (float*)d_ws;
  float* WT       = ws;                          // 1024*2048            = 2,097,152 f
  float* partials = ws + 2097152;                // 2048*32*16           = 1,048,576 f
  float* hbuf     = ws + 3145728;                // 2*32*512             =    32,768 f
  float* cbuf     = ws + 3178496;                // 32*512               =    16,384 f
  unsigned long long* keys = (unsigned long long*)(ws + 3194880);  // 64 u64 = 128 f
  unsigned short* hs = (unsigned short*)(ws + 3195008);            // 3*32*512 u16 = 24,576 f
  float* Wp32 = ws + 3219584;                    // 32000*512 f = 65.5 MB

  k_init<<<64, 256, 0, stream>>>(z, Wh, bh, Wc, bc, hbuf, cbuf, keys);
  k_transposeW<<<dim3(64, 32), 256, 0, stream>>>(Wih, Whh, WT);
  k_packW32<<<2000, 256, 0, stream>>>(Wfc, Wp32);

  void* args[] = {(void*)&WT,   (void*)&emb,  (void*)&bih, (void*)&bhh,
                  (void*)&Wp32, (void*)&bfc,  (void*)&out, (void*)&hbuf,
                  (void*)&cbuf, (void*)&hs,   (void*)&keys, (void*)&partials};
  hipLaunchCooperativeKernel((const void*)decoder, dim3(256), dim3(512), args, 0, stream);
}

// Round 16
// 5775.883 us; speedup vs baseline: 4.1922x; 4.1922x over previous
//
#include <hip/hip_runtime.h>
#include <hip/hip_bf16.h>
#include <cstdint>
#include <cstddef>

#define NB 32
#define NL 256
#define NH 512
#define NE 512
#define NV 32000
#define NT 64
#define NJ 2048   // 4*H
#define NK 1024   // E+H
#define NKT 16    // k-chunks in gates partial GEMM (NK/64)

typedef __attribute__((ext_vector_type(8))) short bf16x8;
typedef __attribute__((ext_vector_type(4))) float f32x4;

// ---------------- helpers ----------------

__device__ __forceinline__ unsigned int sortable_f32(float f) {
  unsigned int s = __float_as_uint(f);
  return (s & 0x80000000u) ? ~s : (s | 0x80000000u);
}

__device__ __forceinline__ unsigned long long pack_key(float f, int v) {
  // high 32: sortable float; low 32: ~v so ties pick smallest v (numpy argmax)
  return ((unsigned long long)sortable_f32(f) << 32) |
         (unsigned long long)(unsigned int)(~v);
}

__device__ __forceinline__ unsigned long long shfl_xor_u64(unsigned long long x, int m) {
  unsigned int lo = (unsigned int)x;
  unsigned int hi = (unsigned int)(x >> 32);
  lo = __shfl_xor(lo, m, 64);
  hi = __shfl_xor(hi, m, 64);
  return ((unsigned long long)hi << 32) | lo;
}

__device__ __forceinline__ uint32_t pack_hi16(uint32_t u0, uint32_t u1) {
  // result = [hi16(u0) in low half, hi16(u1) in high half]
  return __builtin_amdgcn_perm(u1, u0, 0x07060302u);
}

// exact 3-way bf16 truncation split of 8 fp32 values: e == A1 + A2 + A3 bitwise
__device__ __forceinline__ void split3(float4 wa, float4 wb,
                                       bf16x8& A1, bf16x8& A2, bf16x8& A3) {
  union U { uint32_t w[4]; bf16x8 v; };
  U u1, u2, u3;
  float e[8] = {wa.x, wa.y, wa.z, wa.w, wb.x, wb.y, wb.z, wb.w};
#pragma unroll
  for (int p = 0; p < 4; ++p) {
    float e0 = e[2 * p], e1 = e[2 * p + 1];
    uint32_t a0 = __float_as_uint(e0), a1 = __float_as_uint(e1);
    u1.w[p] = pack_hi16(a0, a1);
    float r0 = e0 - __uint_as_float(a0 & 0xffff0000u);
    float r1 = e1 - __uint_as_float(a1 & 0xffff0000u);
    uint32_t b0 = __float_as_uint(r0), b1 = __float_as_uint(r1);
    u2.w[p] = pack_hi16(b0, b1);
    float q0 = r0 - __uint_as_float(b0 & 0xffff0000u);
    float q1 = r1 - __uint_as_float(b1 & 0xffff0000u);
    u3.w[p] = pack_hi16(__float_as_uint(q0), __float_as_uint(q1));
  }
  A1 = u1.v; A2 = u2.v; A3 = u3.v;
}

// device-scope coherent key load (atomic-write -> atomic-read across dispatches)
__device__ __forceinline__ unsigned long long load_key(const unsigned long long* p) {
  return __hip_atomic_load(p, __ATOMIC_ACQUIRE, __HIP_MEMORY_SCOPE_AGENT);
}

// ---------------- kernels ----------------

// K0: h0 = z@Wh.T + bh ; c0 = z@Wc.T + bc ; zero argmax keys + arrival counter
__global__ void k_init(const float* __restrict__ z, const float* __restrict__ Wh,
                       const float* __restrict__ bh, const float* __restrict__ Wc,
                       const float* __restrict__ bc, float* __restrict__ hbuf,
                       float* __restrict__ cbuf, unsigned long long* __restrict__ keys,
                       unsigned int* __restrict__ counter) {
  int idx = blockIdx.x * 256 + threadIdx.x;   // 0..16383
  int b = idx >> 9, hh = idx & 511;
  const float* zr  = z + b * NL;
  const float* whr = Wh + hh * NL;
  const float* wcr = Wc + hh * NL;
  float ah = 0.f, ac = 0.f;
  for (int k = 0; k < NL; ++k) {
    float zv = zr[k];
    ah += zv * whr[k];
    ac += zv * wcr[k];
  }
  hbuf[b * NH + hh] = ah + bh[hh];   // hbuf slot 0 (input of step 0; also x0)
  cbuf[b * NH + hh] = ac + bc[hh];
  if (idx < 64)
    __hip_atomic_store(&keys[idx], 0ULL, __ATOMIC_RELEASE, __HIP_MEMORY_SCOPE_AGENT);
  if (idx == 64)
    __hip_atomic_store(counter, 0u, __ATOMIC_RELEASE, __HIP_MEMORY_SCOPE_AGENT);
}

// K0b: WT[k][j] = (k<E ? Wih[j][k] : Whh[j][k-E])   (tiled transpose, once)
__global__ void k_transposeW(const float* __restrict__ Wih, const float* __restrict__ Whh,
                             float* __restrict__ WT) {
  __shared__ float tile[32][33];
  int j0 = blockIdx.x * 32;   // 64 tiles over NJ
  int k0 = blockIdx.y * 32;   // 32 tiles over NK
  int tx = threadIdx.x & 31;
  int ty = threadIdx.x >> 5;
  for (int r = ty; r < 32; r += 8) {
    int j = j0 + r, k = k0 + tx;
    tile[r][tx] = (k < NE) ? Wih[j * NE + k] : Whh[j * NH + (k - NE)];
  }
  __syncthreads();
  for (int r = ty; r < 32; r += 8) {
    int k = k0 + r, j = j0 + tx;
    WT[(size_t)k * NJ + j] = tile[tx][r];
  }
}

// K0c: one-time pack of Wfc into wave-linear fp32 fragments (no precision change).
// Fragment c = wg*16 + kq (wg in [0,2000), kq in [0,16)) is 512 floats; lane l
// holds floats [l*8, l*8+8) = row (wg*16 + (l&15)), k = kq*32 + (l>>4)*8 .. +8.
__global__ void k_packW32(const float* __restrict__ Wfc, float* __restrict__ Wp32) {
  int bid = blockIdx.x;                 // wg in [0,2000)
  int tid = threadIdx.x;
  int lane = tid & 63, wv = tid >> 6;   // 4 waves
  int r16 = lane & 15, g = lane >> 4;
  const float* wr = Wfc + (size_t)(bid * 16 + r16) * NH + g * 8;
#pragma unroll
  for (int q = 0; q < 4; ++q) {
    int kq = wv * 4 + q;
    float4 wa = *(const float4*)(wr + kq * 32);
    float4 wb = *(const float4*)(wr + kq * 32 + 4);
    float* dst = Wp32 + ((size_t)(bid * 16 + kq) << 9) + lane * 8;
    *(float4*)dst = wa;
    *(float4*)(dst + 4) = wb;
  }
}

// K1+K2 in one dispatch via fence+counter (NO grid.sync):
//  blocks 0..255  : r11 k_gates verbatim (jx = bid&15, ktb = bid>>4), then
//                   __threadfence + atomicAdd(counter).
//  blocks 256..319: spin on counter >= 256*(step+1), then r11 k_cell verbatim
//                   (cb = bid-256 as old blockIdx.x).
__global__ __launch_bounds__(256) void k_gc(
    const float* __restrict__ WT, const float* __restrict__ emb,
    const float* __restrict__ hbuf, unsigned long long* __restrict__ keys,
    float* __restrict__ partials, const float* __restrict__ bih,
    const float* __restrict__ bhh, float* __restrict__ hbuf_w,
    float* __restrict__ cbuf, unsigned short* __restrict__ hs,
    unsigned int* __restrict__ counter, int step) {
  __shared__ unsigned int spred[NB];
  const int tid = threadIdx.x;
  const int bid = blockIdx.x;

  if (bid < 256) {
    // ---------------- gates (r11 k_gates verbatim) ----------------
    const int jx = bid & 15, ktb = bid >> 4;
    int jthr = tid & 31, bthr = tid >> 5;
    int j0 = jx * 128 + jthr * 4;
    int k0 = ktb * 64;
    int b0 = bthr * 4;
    const float* hin = hbuf + (size_t)(step & 1) * NB * NH;
    const bool isx = (k0 < NE);

    if (step > 0 && isx && tid < NB) {
      unsigned long long key = load_key(&keys[((step - 1) & 1) * NB + tid]);
      unsigned int pred = ~(unsigned int)(key & 0xFFFFFFFFu);
      if (pred >= NV) pred = 0;       // defensive; never triggers in a correct run
      spred[tid] = pred;
    }
    __syncthreads();

    const float* xp[4];
#pragma unroll
    for (int i = 0; i < 4; ++i) {
      int b = b0 + i;
      if (!isx) {
        xp[i] = hin + (size_t)b * NH - NE;
      } else if (step == 0) {
        xp[i] = hin + (size_t)b * NE;   // x0 = h0 (E==H)
      } else {
        xp[i] = emb + (size_t)spred[b] * NE;
      }
    }

    float acc[4][4];
#pragma unroll
    for (int jj = 0; jj < 4; ++jj)
#pragma unroll
      for (int i = 0; i < 4; ++i) acc[jj][i] = 0.f;

#pragma unroll 4
    for (int k = k0; k < k0 + 64; ++k) {
      float4 w = *(const float4*)(WT + (size_t)k * NJ + j0);
#pragma unroll
      for (int i = 0; i < 4; ++i) {
        float xv = xp[i][k];
        acc[0][i] += w.x * xv;
        acc[1][i] += w.y * xv;
        acc[2][i] += w.z * xv;
        acc[3][i] += w.w * xv;
      }
    }

#pragma unroll
    for (int jj = 0; jj < 4; ++jj)
#pragma unroll
      for (int i = 0; i < 4; ++i)
        partials[((size_t)(j0 + jj) * NB + (b0 + i)) * NKT + ktb] = acc[jj][i];

    __threadfence();                   // release partials
    __syncthreads();                   // all stores in this block issued
    if (tid == 0) atomicAdd(counter, 1u);
  } else {
    // ---------------- cell (r11 k_cell verbatim, after arrival wait) --------
    const unsigned int target = 256u * (unsigned int)(step + 1);
    if (tid == 0) {
      while (__hip_atomic_load(counter, __ATOMIC_ACQUIRE, __HIP_MEMORY_SCOPE_AGENT) < target)
        __builtin_amdgcn_s_sleep(8);
    }
    __syncthreads();
    // per-thread acquire so every lane orders its partials reads
    (void)__hip_atomic_load(counter, __ATOMIC_ACQUIRE, __HIP_MEMORY_SCOPE_AGENT);

    const int cb = bid - 256;
    int idx = cb * 256 + tid;          // 0..16383
    int b = idx >> 9, hh = idx & 511;
    float g4[4];
#pragma unroll
    for (int g = 0; g < 4; ++g) {
      int j = g * NH + hh;
      const float4* p4 = (const float4*)(partials + ((size_t)j * NB + b) * NKT);
      float4 a0 = p4[0], a1 = p4[1], a2 = p4[2], a3 = p4[3];
      float s = ((a0.x + a0.y) + (a0.z + a0.w)) + ((a1.x + a1.y) + (a1.z + a1.w)) +
                ((a2.x + a2.y) + (a2.z + a2.w)) + ((a3.x + a3.y) + (a3.z + a3.w));
      g4[g] = s + bih[j] + bhh[j];
    }
    float ig = 1.0f / (1.0f + expf(-g4[0]));
    float fg = 1.0f / (1.0f + expf(-g4[1]));
    float gg = tanhf(g4[2]);
    float og = 1.0f / (1.0f + expf(-g4[3]));
    float c  = cbuf[b * NH + hh];
    float cn = fg * c + ig * gg;
    float hn = og * tanhf(cn);
    cbuf[b * NH + hh] = cn;
    hbuf_w[(size_t)((step + 1) & 1) * NB * NH + b * NH + hh] = hn;

    // exact 3-way bf16 truncation split: hn == h1 + h2 + h3
    uint32_t u = __float_as_uint(hn);
    float r1 = hn - __uint_as_float(u & 0xffff0000u);
    uint32_t u2 = __float_as_uint(r1);
    float r2 = r1 - __uint_as_float(u2 & 0xffff0000u);
    uint32_t u3 = __float_as_uint(r2);
    hs[0 * NB * NH + b * NH + hh] = (unsigned short)(u >> 16);
    hs[1 * NB * NH + b * NH + hh] = (unsigned short)(u2 >> 16);
    hs[2 * NB * NH + b * NH + hh] = (unsigned short)(u3 >> 16);

    // reset the key slot k_logits is about to accumulate into (device-scope store)
    if (idx < NB)
      __hip_atomic_store(&keys[(step & 1) * NB + idx], 0ULL,
                         __ATOMIC_RELEASE, __HIP_MEMORY_SCOPE_AGENT);
  }
}

// K3: logits = h_new @ Wfc.T + bfc via packed fp32 + on-the-fly split3 + MFMA.
// grid 250 x 512 (8 waves); wave -> 16 v rows; block -> 128 v, all 32 b.
// Single LDS stage of all K=512; depth-2 raw prefetch (separate regs, shift
// AFTER the MFMAs — round-8 proven form); split3 of kq+1 overlaps kq's MFMAs.
__global__ __launch_bounds__(512, 1) void k_logits3(
    const float* __restrict__ Wp32, const float* __restrict__ bfc,
    const unsigned short* __restrict__ hs, float* __restrict__ out,
    unsigned long long* __restrict__ keys, int step) {
  __shared__ __align__(16) unsigned short H[3][32][520];  // pitch 1040B
  __shared__ __align__(16) float tbuf[32][132];           // out transpose tile
  __shared__ unsigned long long kmax[32];

  const int tid = threadIdx.x, bid = blockIdx.x;
  const int lane = tid & 63, wid = tid >> 6;
  const int r16 = lane & 15, g = lane >> 4;

  const int wg = bid * 8 + wid;                       // global wave id [0,2000)
  const float* wbase = Wp32 + ((size_t)wg << 13) + lane * 8;   // wg*16*512

  // prologue: raw fp32 for kq=0,1 (overlaps the LDS staging below)
  float4 wa0 = *(const float4*)(wbase);
  float4 wb0 = *(const float4*)(wbase + 4);
  float4 wan = *(const float4*)(wbase + 512);
  float4 wbn = *(const float4*)(wbase + 512 + 4);

  // stage all 3 h-split planes: 6144 float4 chunks, 12 per thread, coalesced
#pragma unroll
  for (int i = 0; i < 12; ++i) {
    int idx = tid + i * 512;
    int s = idx >> 11, rem = idx & 2047;
    int row = rem >> 6, ch = rem & 63;
    float4 d = *(const float4*)(hs + (size_t)s * (NB * NH) + row * NH + ch * 8);
    *(float4*)(&H[s][row][ch * 8]) = d;
  }
  if (tid < 32) kmax[tid] = 0ULL;

  bf16x8 Acur[3];
  split3(wa0, wb0, Acur[0], Acur[1], Acur[2]);
  __syncthreads();

  f32x4 acc0 = {0.f, 0.f, 0.f, 0.f};
  f32x4 acc1 = {0.f, 0.f, 0.f, 0.f};

#pragma unroll
  for (int kq = 0; kq < 16; ++kq) {
    float4 wa2, wb2;
    if (kq < 14) {
      wa2 = *(const float4*)(wbase + (size_t)(kq + 2) * 512);
      wb2 = *(const float4*)(wbase + (size_t)(kq + 2) * 512 + 4);
    }
    bf16x8 Anx[3];
    if (kq < 15) split3(wan, wbn, Anx[0], Anx[1], Anx[2]);

    const int ko = kq * 32 + g * 8;
    bf16x8 B1n0 = *(const bf16x8*)(&H[0][r16][ko]);
    bf16x8 B1n1 = *(const bf16x8*)(&H[0][r16 + 16][ko]);
    bf16x8 B2n0 = *(const bf16x8*)(&H[1][r16][ko]);
    bf16x8 B2n1 = *(const bf16x8*)(&H[1][r16 + 16][ko]);
    bf16x8 B3n0 = *(const bf16x8*)(&H[2][r16][ko]);
    bf16x8 B3n1 = *(const bf16x8*)(&H[2][r16 + 16][ko]);

    acc0 = __builtin_amdgcn_mfma_f32_16x16x32_bf16(Acur[0], B1n0, acc0, 0, 0, 0);
    acc0 = __builtin_amdgcn_mfma_f32_16x16x32_bf16(Acur[0], B2n0, acc0, 0, 0, 0);
    acc0 = __builtin_amdgcn_mfma_f32_16x16x32_bf16(Acur[1], B1n0, acc0, 0, 0, 0);
    acc0 = __builtin_amdgcn_mfma_f32_16x16x32_bf16(Acur[1], B2n0, acc0, 0, 0, 0);
    acc0 = __builtin_amdgcn_mfma_f32_16x16x32_bf16(Acur[0], B3n0, acc0, 0, 0, 0);
    acc0 = __builtin_amdgcn_mfma_f32_16x16x32_bf16(Acur[2], B1n0, acc0, 0, 0, 0);

    acc1 = __builtin_amdgcn_mfma_f32_16x16x32_bf16(Acur[0], B1n1, acc1, 0, 0, 0);
    acc1 = __builtin_amdgcn_mfma_f32_16x16x32_bf16(Acur[0], B2n1, acc1, 0, 0, 0);
    acc1 = __builtin_amdgcn_mfma_f32_16x16x32_bf16(Acur[1], B1n1, acc1, 0, 0, 0);
    acc1 = __builtin_amdgcn_mfma_f32_16x16x32_bf16(Acur[1], B2n1, acc1, 0, 0, 0);
    acc1 = __builtin_amdgcn_mfma_f32_16x16x32_bf16(Acur[0], B3n1, acc1, 0, 0, 0);
    acc1 = __builtin_amdgcn_mfma_f32_16x16x32_bf16(Acur[2], B1n1, acc1, 0, 0, 0);

    if (kq < 15) {
#pragma unroll
      for (int s = 0; s < 3; ++s) Acur[s] = Anx[s];
      wan = wa2; wbn = wb2;
    }
  }

  // epilogue: bias, argmax keys, transposed coalesced store
  // C/D layout (verified): col = lane&15 (b within n-frag), row = 4*(lane>>4)+reg (v)
  const int vwave = bid * 128 + wid * 16;
  float4 bv = *(const float4*)(bfc + vwave + g * 4);
  float lg0[4], lg1[4];
  unsigned long long key0 = 0ULL, key1 = 0ULL;
#pragma unroll
  for (int reg = 0; reg < 4; ++reg) {
    int v = vwave + 4 * g + reg;
    float bvr = (reg == 0) ? bv.x : (reg == 1) ? bv.y : (reg == 2) ? bv.z : bv.w;
    lg0[reg] = acc0[reg] + bvr;
    lg1[reg] = acc1[reg] + bvr;
    unsigned long long p0 = pack_key(lg0[reg], v);
    unsigned long long p1 = pack_key(lg1[reg], v);
    key0 = (p0 > key0) ? p0 : key0;
    key1 = (p1 > key1) ? p1 : key1;
  }
#pragma unroll
  for (int m = 16; m <= 32; m <<= 1) {
    unsigned long long o0 = shfl_xor_u64(key0, m);
    unsigned long long o1 = shfl_xor_u64(key1, m);
    key0 = (o0 > key0) ? o0 : key0;
    key1 = (o1 > key1) ? o1 : key1;
  }
  if (g == 0) {
    atomicMax(&kmax[r16], key0);
    atomicMax(&kmax[r16 + 16], key1);
  }
  __syncthreads();   // kmax atomics complete before anything else proceeds

  // write transposed tile: tbuf[b][v_local]
#pragma unroll
  for (int reg = 0; reg < 4; ++reg) {
    int vloc = wid * 16 + 4 * g + reg;
    tbuf[r16][vloc] = lg0[reg];
    tbuf[r16 + 16][vloc] = lg1[reg];
  }
  __syncthreads();

  // coalesced nontemporal store: 128 x 32 tile, 4096 floats, 8 per thread
  {
    int bb = tid >> 4, seg = tid & 15;
    f32x4 p0 = *(const f32x4*)(&tbuf[bb][seg * 8]);
    f32x4 p1 = *(const f32x4*)(&tbuf[bb][seg * 8 + 4]);
    float* dst = out + ((size_t)bb * NT + step) * NV + bid * 128 + seg * 8;
    __builtin_nontemporal_store(p0, (f32x4*)dst);
    __builtin_nontemporal_store(p1, (f32x4*)(dst + 4));
  }
  if (tid < 32) atomicMax(&keys[(step & 1) * NB + tid], kmax[tid]);
}

// ---------------- host ----------------

extern "C" void kernel_launch(void* const* d_in, const int* in_sizes, int n_in,
                              void* d_out, int out_size, void* d_ws, size_t ws_size,
                              hipStream_t stream) {
  (void)in_sizes; (void)n_in; (void)out_size; (void)ws_size;
  const float* z   = (const float*)d_in[0];
  const float* emb = (const float*)d_in[1];
  const float* Wh  = (const float*)d_in[2];
  const float* bh  = (const float*)d_in[3];
  const float* Wc  = (const float*)d_in[4];
  const float* bc  = (const float*)d_in[5];
  const float* Wih = (const float*)d_in[6];
  const float* Whh = (const float*)d_in[7];
  const float* bih = (const float*)d_in[8];
  const float* bhh = (const float*)d_in[9];
  const float* Wfc = (const float*)d_in[10];
  const float* bfc = (const float*)d_in[11];
  float* out = (float*)d_out;

  float* ws = (float*)d_ws;
  float* WT       = ws;                          // 1024*2048            = 2,097,152 f
  float* partials = ws + 2097152;                // 2048*32*16           = 1,048,576 f
  float* hbuf     = ws + 3145728;                // 2*32*512             =    32,768 f
  float* cbuf     = ws + 3178496;                // 32*512               =    16,384 f
  unsigned long long* keys = (unsigned long long*)(ws + 3194880);  // 64 u64 = 128 f
  unsigned short* hs = (unsigned short*)(ws + 3195008);            // 3*32*512 u16 = 24,576 f
  float* Wp32 = ws + 3219584;                    // 32000*512 f = 65.5 MB (ends 19,603,584)
  unsigned int* counter = (unsigned int*)(ws + 19603584);

  k_init<<<64, 256, 0, stream>>>(z, Wh, bh, Wc, bc, hbuf, cbuf, keys, counter);
  k_transposeW<<<dim3(64, 32), 256, 0, stream>>>(Wih, Whh, WT);
  k_packW32<<<2000, 256, 0, stream>>>(Wfc, Wp32);

  for (int t = 0; t < NT; ++t) {
    k_gc<<<320, 256, 0, stream>>>(WT, emb, hbuf, keys, partials, bih, bhh,
                                  hbuf, cbuf, hs, counter, t);
    k_logits3<<<250, 512, 0, stream>>>(Wp32, bfc, hs, out, keys, t);
  }
}

// Round 17
// 2744.084 us; speedup vs baseline: 8.8239x; 2.1048x over previous
//
#include <hip/hip_runtime.h>
#include <hip/hip_bf16.h>
#include <cstdint>
#include <cstddef>

#define NB 32
#define NL 256
#define NH 512
#define NE 512
#define NV 32000
#define NT 64
#define NJ 2048   // 4*H
#define NK 1024   // E+H
#define NKT 16    // k-chunks in gates partial GEMM (NK/64)

typedef __attribute__((ext_vector_type(8))) short bf16x8;
typedef __attribute__((ext_vector_type(4))) float f32x4;

// ---------------- helpers ----------------

__device__ __forceinline__ unsigned int sortable_f32(float f) {
  unsigned int s = __float_as_uint(f);
  return (s & 0x80000000u) ? ~s : (s | 0x80000000u);
}

__device__ __forceinline__ unsigned long long pack_key(float f, int v) {
  // high 32: sortable float; low 32: ~v so ties pick smallest v (numpy argmax)
  return ((unsigned long long)sortable_f32(f) << 32) |
         (unsigned long long)(unsigned int)(~v);
}

__device__ __forceinline__ unsigned long long shfl_xor_u64(unsigned long long x, int m) {
  unsigned int lo = (unsigned int)x;
  unsigned int hi = (unsigned int)(x >> 32);
  lo = __shfl_xor(lo, m, 64);
  hi = __shfl_xor(hi, m, 64);
  return ((unsigned long long)hi << 32) | lo;
}

__device__ __forceinline__ uint32_t pack_hi16(uint32_t u0, uint32_t u1) {
  // result = [hi16(u0) in low half, hi16(u1) in high half]
  return __builtin_amdgcn_perm(u1, u0, 0x07060302u);
}

// exact 3-way bf16 truncation split of 8 fp32 values: e == A1 + A2 + A3 bitwise
__device__ __forceinline__ void split3(float4 wa, float4 wb,
                                       bf16x8& A1, bf16x8& A2, bf16x8& A3) {
  union U { uint32_t w[4]; bf16x8 v; };
  U u1, u2, u3;
  float e[8] = {wa.x, wa.y, wa.z, wa.w, wb.x, wb.y, wb.z, wb.w};
#pragma unroll
  for (int p = 0; p < 4; ++p) {
    float e0 = e[2 * p], e1 = e[2 * p + 1];
    uint32_t a0 = __float_as_uint(e0), a1 = __float_as_uint(e1);
    u1.w[p] = pack_hi16(a0, a1);
    float r0 = e0 - __uint_as_float(a0 & 0xffff0000u);
    float r1 = e1 - __uint_as_float(a1 & 0xffff0000u);
    uint32_t b0 = __float_as_uint(r0), b1 = __float_as_uint(r1);
    u2.w[p] = pack_hi16(b0, b1);
    float q0 = r0 - __uint_as_float(b0 & 0xffff0000u);
    float q1 = r1 - __uint_as_float(b1 & 0xffff0000u);
    u3.w[p] = pack_hi16(__float_as_uint(q0), __float_as_uint(q1));
  }
  A1 = u1.v; A2 = u2.v; A3 = u3.v;
}

// device-scope coherent key load (atomic-write -> atomic-read across dispatches)
__device__ __forceinline__ unsigned long long load_key(const unsigned long long* p) {
  return __hip_atomic_load(p, __ATOMIC_ACQUIRE, __HIP_MEMORY_SCOPE_AGENT);
}

// ---------------- kernels ----------------

// K0: h0 = z@Wh.T + bh ; c0 = z@Wc.T + bc ; zero argmax keys
__global__ void k_init(const float* __restrict__ z, const float* __restrict__ Wh,
                       const float* __restrict__ bh, const float* __restrict__ Wc,
                       const float* __restrict__ bc, float* __restrict__ hbuf,
                       float* __restrict__ cbuf, unsigned long long* __restrict__ keys) {
  int idx = blockIdx.x * 256 + threadIdx.x;   // 0..16383
  int b = idx >> 9, hh = idx & 511;
  const float* zr  = z + b * NL;
  const float* whr = Wh + hh * NL;
  const float* wcr = Wc + hh * NL;
  float ah = 0.f, ac = 0.f;
  for (int k = 0; k < NL; ++k) {
    float zv = zr[k];
    ah += zv * whr[k];
    ac += zv * wcr[k];
  }
  hbuf[b * NH + hh] = ah + bh[hh];   // hbuf slot 0 (input of step 0; also x0)
  cbuf[b * NH + hh] = ac + bc[hh];
  if (idx < 64)
    __hip_atomic_store(&keys[idx], 0ULL, __ATOMIC_RELEASE, __HIP_MEMORY_SCOPE_AGENT);
}

// K0b: WT[k][j] = (k<E ? Wih[j][k] : Whh[j][k-E])   (tiled transpose, once)
__global__ void k_transposeW(const float* __restrict__ Wih, const float* __restrict__ Whh,
                             float* __restrict__ WT) {
  __shared__ float tile[32][33];
  int j0 = blockIdx.x * 32;   // 64 tiles over NJ
  int k0 = blockIdx.y * 32;   // 32 tiles over NK
  int tx = threadIdx.x & 31;
  int ty = threadIdx.x >> 5;
  for (int r = ty; r < 32; r += 8) {
    int j = j0 + r, k = k0 + tx;
    tile[r][tx] = (k < NE) ? Wih[j * NE + k] : Whh[j * NH + (k - NE)];
  }
  __syncthreads();
  for (int r = ty; r < 32; r += 8) {
    int k = k0 + r, j = j0 + tx;
    WT[(size_t)k * NJ + j] = tile[tx][r];
  }
}

// K0c: one-time pack of Wfc into wave-linear fp32 fragments (no precision change).
// Fragment c = wg*16 + kq (wg in [0,2000), kq in [0,16)) is 512 floats; lane l
// holds floats [l*8, l*8+8) = row (wg*16 + (l&15)), k = kq*32 + (l>>4)*8 .. +8.
// Consumer reads frag at Wp32 + c*512 + lane*8 -> two coalesced 1KB bursts.
__global__ void k_packW32(const float* __restrict__ Wfc, float* __restrict__ Wp32) {
  int bid = blockIdx.x;                 // wg in [0,2000)
  int tid = threadIdx.x;
  int lane = tid & 63, wv = tid >> 6;   // 4 waves
  int r16 = lane & 15, g = lane >> 4;
  const float* wr = Wfc + (size_t)(bid * 16 + r16) * NH + g * 8;
#pragma unroll
  for (int q = 0; q < 4; ++q) {
    int kq = wv * 4 + q;
    float4 wa = *(const float4*)(wr + kq * 32);
    float4 wb = *(const float4*)(wr + kq * 32 + 4);
    float* dst = Wp32 + ((size_t)(bid * 16 + kq) << 9) + lane * 8;
    *(float4*)dst = wa;
    *(float4*)(dst + 4) = wb;
  }
}

// K1: gates partial GEMM.  grid (16 j-tiles, 16 k-chunks) x 256 threads.
// thread owns 4 consecutive j, 4 b, one 64-k chunk. Writes partials[j][b][kt].
// Token keys are acquire-loaded ONCE per block by 32 threads into LDS.
__global__ void k_gates(const float* __restrict__ WT, const float* __restrict__ emb,
                        const float* __restrict__ hbuf, const unsigned long long* __restrict__ keys,
                        float* __restrict__ partials, int step) {
  __shared__ unsigned int spred[NB];
  int tid  = threadIdx.x;
  int jthr = tid & 31, bthr = tid >> 5;
  int j0 = blockIdx.x * 128 + jthr * 4;
  int k0 = blockIdx.y * 64;
  int b0 = bthr * 4;
  const float* hin = hbuf + (size_t)(step & 1) * NB * NH;
  const bool isx = (k0 < NE);

  if (step > 0 && isx && tid < NB) {
    unsigned long long key = load_key(&keys[((step - 1) & 1) * NB + tid]);
    unsigned int pred = ~(unsigned int)(key & 0xFFFFFFFFu);
    if (pred >= NV) pred = 0;       // defensive; never triggers in a correct run
    spred[tid] = pred;
  }
  __syncthreads();

  const float* xp[4];
#pragma unroll
  for (int i = 0; i < 4; ++i) {
    int b = b0 + i;
    if (!isx) {
      xp[i] = hin + (size_t)b * NH - NE;
    } else if (step == 0) {
      xp[i] = hin + (size_t)b * NE;   // x0 = h0 (E==H)
    } else {
      xp[i] = emb + (size_t)spred[b] * NE;
    }
  }

  float acc[4][4];
#pragma unroll
  for (int jj = 0; jj < 4; ++jj)
#pragma unroll
    for (int i = 0; i < 4; ++i) acc[jj][i] = 0.f;

#pragma unroll 4
  for (int k = k0; k < k0 + 64; ++k) {
    float4 w = *(const float4*)(WT + (size_t)k * NJ + j0);
#pragma unroll
    for (int i = 0; i < 4; ++i) {
      float xv = xp[i][k];
      acc[0][i] += w.x * xv;
      acc[1][i] += w.y * xv;
      acc[2][i] += w.z * xv;
      acc[3][i] += w.w * xv;
    }
  }

  int kt = blockIdx.y;
#pragma unroll
  for (int jj = 0; jj < 4; ++jj)
#pragma unroll
    for (int i = 0; i < 4; ++i)
      partials[((size_t)(j0 + jj) * NB + (b0 + i)) * NKT + kt] = acc[jj][i];
}

// K2: reduce partials -> gates -> cell update -> h_new (fp32 + exact bf16 3-way split).
__global__ void k_cell(const float* __restrict__ partials, const float* __restrict__ bih,
                       const float* __restrict__ bhh, float* __restrict__ hbuf,
                       float* __restrict__ cbuf, unsigned short* __restrict__ hs,
                       unsigned long long* __restrict__ keys, int step) {
  int idx = blockIdx.x * 256 + threadIdx.x;  // 0..16383
  int b = idx >> 9, hh = idx & 511;
  float g4[4];
#pragma unroll
  for (int g = 0; g < 4; ++g) {
    int j = g * NH + hh;
    const float4* p4 = (const float4*)(partials + ((size_t)j * NB + b) * NKT);
    float4 a0 = p4[0], a1 = p4[1], a2 = p4[2], a3 = p4[3];
    float s = ((a0.x + a0.y) + (a0.z + a0.w)) + ((a1.x + a1.y) + (a1.z + a1.w)) +
              ((a2.x + a2.y) + (a2.z + a2.w)) + ((a3.x + a3.y) + (a3.z + a3.w));
    g4[g] = s + bih[j] + bhh[j];
  }
  float ig = 1.0f / (1.0f + expf(-g4[0]));
  float fg = 1.0f / (1.0f + expf(-g4[1]));
  float gg = tanhf(g4[2]);
  float og = 1.0f / (1.0f + expf(-g4[3]));
  float c  = cbuf[b * NH + hh];
  float cn = fg * c + ig * gg;
  float hn = og * tanhf(cn);
  cbuf[b * NH + hh] = cn;
  hbuf[(size_t)((step + 1) & 1) * NB * NH + b * NH + hh] = hn;

  // exact 3-way bf16 truncation split: hn == h1 + h2 + h3
  uint32_t u = __float_as_uint(hn);
  float r1 = hn - __uint_as_float(u & 0xffff0000u);
  uint32_t u2 = __float_as_uint(r1);
  float r2 = r1 - __uint_as_float(u2 & 0xffff0000u);
  uint32_t u3 = __float_as_uint(r2);
  hs[0 * NB * NH + b * NH + hh] = (unsigned short)(u >> 16);
  hs[1 * NB * NH + b * NH + hh] = (unsigned short)(u2 >> 16);
  hs[2 * NB * NH + b * NH + hh] = (unsigned short)(u3 >> 16);

  // reset the key slot k_logits is about to accumulate into (device-scope store)
  if (idx < NB)
    __hip_atomic_store(&keys[(step & 1) * NB + idx], 0ULL,
                       __ATOMIC_RELEASE, __HIP_MEMORY_SCOPE_AGENT);
}

// K3: logits = h_new @ Wfc.T + bfc via packed fp32 + on-the-fly split3 + MFMA.
// grid 250 x 512 (8 waves); wave -> 16 v rows; block -> 128 v, all 32 b.
// Single LDS stage of all K=512; depth-2 raw prefetch (separate regs, shift
// AFTER the MFMAs — round-8 proven form); split3 of kq+1 overlaps kq's MFMAs.
__global__ __launch_bounds__(512, 1) void k_logits3(
    const float* __restrict__ Wp32, const float* __restrict__ bfc,
    const unsigned short* __restrict__ hs, float* __restrict__ out,
    unsigned long long* __restrict__ keys, int step) {
  __shared__ __align__(16) unsigned short H[3][32][520];  // pitch 1040B
  __shared__ __align__(16) float tbuf[32][132];           // out transpose tile
  __shared__ unsigned long long kmax[32];

  const int tid = threadIdx.x, bid = blockIdx.x;
  const int lane = tid & 63, wid = tid >> 6;
  const int r16 = lane & 15, g = lane >> 4;

  const int wg = bid * 8 + wid;                       // global wave id [0,2000)
  const float* wbase = Wp32 + ((size_t)wg << 13) + lane * 8;   // wg*16*512

  // prologue: raw fp32 for kq=0,1 (overlaps the LDS staging below)
  float4 wa0 = *(const float4*)(wbase);
  float4 wb0 = *(const float4*)(wbase + 4);
  float4 wan = *(const float4*)(wbase + 512);
  float4 wbn = *(const float4*)(wbase + 512 + 4);

  // stage all 3 h-split planes: 6144 float4 chunks, 12 per thread, coalesced
#pragma unroll
  for (int i = 0; i < 12; ++i) {
    int idx = tid + i * 512;
    int s = idx >> 11, rem = idx & 2047;
    int row = rem >> 6, ch = rem & 63;
    float4 d = *(const float4*)(hs + (size_t)s * (NB * NH) + row * NH + ch * 8);
    *(float4*)(&H[s][row][ch * 8]) = d;
  }
  if (tid < 32) kmax[tid] = 0ULL;

  bf16x8 Acur[3];
  split3(wa0, wb0, Acur[0], Acur[1], Acur[2]);
  __syncthreads();

  f32x4 acc0 = {0.f, 0.f, 0.f, 0.f};
  f32x4 acc1 = {0.f, 0.f, 0.f, 0.f};

#pragma unroll
  for (int kq = 0; kq < 16; ++kq) {
    float4 wa2, wb2;
    if (kq < 14) {
      wa2 = *(const float4*)(wbase + (size_t)(kq + 2) * 512);
      wb2 = *(const float4*)(wbase + (size_t)(kq + 2) * 512 + 4);
    }
    bf16x8 Anx[3];
    if (kq < 15) split3(wan, wbn, Anx[0], Anx[1], Anx[2]);

    const int ko = kq * 32 + g * 8;
    bf16x8 B1n0 = *(const bf16x8*)(&H[0][r16][ko]);
    bf16x8 B1n1 = *(const bf16x8*)(&H[0][r16 + 16][ko]);
    bf16x8 B2n0 = *(const bf16x8*)(&H[1][r16][ko]);
    bf16x8 B2n1 = *(const bf16x8*)(&H[1][r16 + 16][ko]);
    bf16x8 B3n0 = *(const bf16x8*)(&H[2][r16][ko]);
    bf16x8 B3n1 = *(const bf16x8*)(&H[2][r16 + 16][ko]);

    acc0 = __builtin_amdgcn_mfma_f32_16x16x32_bf16(Acur[0], B1n0, acc0, 0, 0, 0);
    acc0 = __builtin_amdgcn_mfma_f32_16x16x32_bf16(Acur[0], B2n0, acc0, 0, 0, 0);
    acc0 = __builtin_amdgcn_mfma_f32_16x16x32_bf16(Acur[1], B1n0, acc0, 0, 0, 0);
    acc0 = __builtin_amdgcn_mfma_f32_16x16x32_bf16(Acur[1], B2n0, acc0, 0, 0, 0);
    acc0 = __builtin_amdgcn_mfma_f32_16x16x32_bf16(Acur[0], B3n0, acc0, 0, 0, 0);
    acc0 = __builtin_amdgcn_mfma_f32_16x16x32_bf16(Acur[2], B1n0, acc0, 0, 0, 0);

    acc1 = __builtin_amdgcn_mfma_f32_16x16x32_bf16(Acur[0], B1n1, acc1, 0, 0, 0);
    acc1 = __builtin_amdgcn_mfma_f32_16x16x32_bf16(Acur[0], B2n1, acc1, 0, 0, 0);
    acc1 = __builtin_amdgcn_mfma_f32_16x16x32_bf16(Acur[1], B1n1, acc1, 0, 0, 0);
    acc1 = __builtin_amdgcn_mfma_f32_16x16x32_bf16(Acur[1], B2n1, acc1, 0, 0, 0);
    acc1 = __builtin_amdgcn_mfma_f32_16x16x32_bf16(Acur[0], B3n1, acc1, 0, 0, 0);
    acc1 = __builtin_amdgcn_mfma_f32_16x16x32_bf16(Acur[2], B1n1, acc1, 0, 0, 0);

    if (kq < 15) {
#pragma unroll
      for (int s = 0; s < 3; ++s) Acur[s] = Anx[s];
      wan = wa2; wbn = wb2;
    }
  }

  // epilogue: bias, argmax keys, transposed coalesced store
  // C/D layout (verified): col = lane&15 (b within n-frag), row = 4*(lane>>4)+reg (v)
  const int vwave = bid * 128 + wid * 16;
  float4 bv = *(const float4*)(bfc + vwave + g * 4);
  float lg0[4], lg1[4];
  unsigned long long key0 = 0ULL, key1 = 0ULL;
#pragma unroll
  for (int reg = 0; reg < 4; ++reg) {
    int v = vwave + 4 * g + reg;
    float bvr = (reg == 0) ? bv.x : (reg == 1) ? bv.y : (reg == 2) ? bv.z : bv.w;
    lg0[reg] = acc0[reg] + bvr;
    lg1[reg] = acc1[reg] + bvr;
    unsigned long long p0 = pack_key(lg0[reg], v);
    unsigned long long p1 = pack_key(lg1[reg], v);
    key0 = (p0 > key0) ? p0 : key0;
    key1 = (p1 > key1) ? p1 : key1;
  }
#pragma unroll
  for (int m = 16; m <= 32; m <<= 1) {
    unsigned long long o0 = shfl_xor_u64(key0, m);
    unsigned long long o1 = shfl_xor_u64(key1, m);
    key0 = (o0 > key0) ? o0 : key0;
    key1 = (o1 > key1) ? o1 : key1;
  }
  if (g == 0) {
    atomicMax(&kmax[r16], key0);
    atomicMax(&kmax[r16 + 16], key1);
  }
  __syncthreads();   // kmax atomics complete before anything else proceeds

  // write transposed tile: tbuf[b][v_local]
#pragma unroll
  for (int reg = 0; reg < 4; ++reg) {
    int vloc = wid * 16 + 4 * g + reg;
    tbuf[r16][vloc] = lg0[reg];
    tbuf[r16 + 16][vloc] = lg1[reg];
  }
  __syncthreads();

  // coalesced nontemporal store: 128 x 32 tile, 4096 floats, 8 per thread
  {
    int bb = tid >> 4, seg = tid & 15;
    f32x4 p0 = *(const f32x4*)(&tbuf[bb][seg * 8]);
    f32x4 p1 = *(const f32x4*)(&tbuf[bb][seg * 8 + 4]);
    float* dst = out + ((size_t)bb * NT + step) * NV + bid * 128 + seg * 8;
    __builtin_nontemporal_store(p0, (f32x4*)dst);
    __builtin_nontemporal_store(p1, (f32x4*)(dst + 4));
  }
  if (tid < 32) atomicMax(&keys[(step & 1) * NB + tid], kmax[tid]);
}

// ---------------- host ----------------

extern "C" void kernel_launch(void* const* d_in, const int* in_sizes, int n_in,
                              void* d_out, int out_size, void* d_ws, size_t ws_size,
                              hipStream_t stream) {
  (void)in_sizes; (void)n_in; (void)out_size; (void)ws_size;
  const float* z   = (const float*)d_in[0];
  const float* emb = (const float*)d_in[1];
  const float* Wh  = (const float*)d_in[2];
  const float* bh  = (const float*)d_in[3];
  const float* Wc  = (const float*)d_in[4];
  const float* bc  = (const float*)d_in[5];
  const float* Wih = (const float*)d_in[6];
  const float* Whh = (const float*)d_in[7];
  const float* bih = (const float*)d_in[8];
  const float* bhh = (const float*)d_in[9];
  const float* Wfc = (const float*)d_in[10];
  const float* bfc = (const float*)d_in[11];
  float* out = (float*)d_out;

  float* ws = (float*)d_ws;
  float* WT       = ws;                          // 1024*2048            = 2,097,152 f
  float* partials = ws + 2097152;                // 2048*32*16           = 1,048,576 f
  float* hbuf     = ws + 3145728;                // 2*32*512             =    32,768 f
  float* cbuf     = ws + 3178496;                // 32*512               =    16,384 f
  unsigned long long* keys = (unsigned long long*)(ws + 3194880);  // 64 u64 = 128 f
  unsigned short* hs = (unsigned short*)(ws + 3195008);            // 3*32*512 u16 = 24,576 f
  float* Wp32 = ws + 3219584;                    // 32000*512 f = 65.5 MB

  k_init<<<64, 256, 0, stream>>>(z, Wh, bh, Wc, bc, hbuf, cbuf, keys);
  k_transposeW<<<dim3(64, 32), 256, 0, stream>>>(Wih, Whh, WT);
  k_packW32<<<2000, 256, 0, stream>>>(Wfc, Wp32);

  for (int t = 0; t < NT; ++t) {
    k_gates<<<dim3(16, 16), 256, 0, stream>>>(WT, emb, hbuf, keys, partials, t);
    k_cell<<<64, 256, 0, stream>>>(partials, bih, bhh, hbuf, cbuf, hs, keys, t);
    k_logits3<<<250, 512, 0, stream>>>(Wp32, bfc, hs, out, keys, t);
  }
}